// Round 1
// baseline (471.824 us; speedup 1.0000x reference)
//
#include <hip/hip_runtime.h>

#define VOCAB 1024
#define HIDDEN 64
#define N_POS 131072            // 32*64*64 positions
#define Q_ELEMS 8388608         // 32*64*64*64
#define BLK 256
#define POS_PER_BLOCK 512
#define CHUNK 256               // codebook rows per LDS chunk

// d_out layout (floats): [0]=loss, [1..8388608]=quantized_st (NCHW),
// [8388609]=perplexity, [8388610..]=one_hot [131072,1024]
#define OUT_Q_OFF 1
#define OUT_PPL_OFF 8388609
#define OUT_OH_OFF 8388610ULL

__global__ void vq_bsq(const float* __restrict__ cb, float* __restrict__ bsq) {
    int j = blockIdx.x * blockDim.x + threadIdx.x;
    if (j < VOCAB) {
        const float4* r = (const float4*)(cb + (size_t)j * HIDDEN);
        float s = 0.f;
#pragma unroll
        for (int c = 0; c < 16; ++c) {
            float4 v = r[c];
            s += v.x * v.x + v.y * v.y + v.z * v.z + v.w * v.w;
        }
        bsq[j] = s;
    }
}

__global__ __launch_bounds__(BLK, 1) void vq_main(
    const float* __restrict__ in, const float* __restrict__ cb,
    const float* __restrict__ bsq, float* __restrict__ out,
    float* __restrict__ ws_loss, unsigned* __restrict__ counts)
{
    __shared__ float cbs[CHUNK * HIDDEN];   // 64 KB
    __shared__ float bsqs[CHUNK];
    __shared__ int   lidx[POS_PER_BLOCK];
    __shared__ unsigned hist[VOCAB];
    __shared__ float lred[4];

    const int tid = threadIdx.x;
    const int n0 = blockIdx.x * POS_PER_BLOCK + tid;
    const int n1 = n0 + BLK;

    // ---- load the two positions' 64-dim vectors into registers ----
    float x0[HIDDEN], x1[HIDDEN];
    {
        const int b0 = n0 >> 12, hw0 = n0 & 4095;
        const int b1 = n1 >> 12, hw1 = n1 & 4095;
        const float* p0 = in + (size_t)b0 * 262144 + hw0;
        const float* p1 = in + (size_t)b1 * 262144 + hw1;
#pragma unroll
        for (int c = 0; c < HIDDEN; ++c) {
            x0[c] = p0[(size_t)c * 4096];   // coalesced across lanes (hw contiguous)
            x1[c] = p1[(size_t)c * 4096];
        }
    }

#pragma unroll
    for (int k = tid; k < VOCAB; k += BLK) hist[k] = 0u;

    float best0 = 3.4e38f, best1 = 3.4e38f;
    int bi0 = 0, bi1 = 0;

    // ---- distance argmin over codebook, chunked through LDS ----
    for (int ch = 0; ch < VOCAB; ch += CHUNK) {
        __syncthreads();
        {
            const float4* src = (const float4*)(cb + (size_t)ch * HIDDEN);
            float4* dst = (float4*)cbs;
#pragma unroll
            for (int k = 0; k < 16; ++k) dst[tid + k * BLK] = src[tid + k * BLK];
            if (tid < CHUNK) bsqs[tid] = bsq[ch + tid];
        }
        __syncthreads();

#pragma unroll 2
        for (int jj = 0; jj < CHUNK; ++jj) {
            const float4* cv = (const float4*)(cbs + jj * HIDDEN);
            float a0 = 0.f, a1 = 0.f, a2 = 0.f, a3 = 0.f;
            float b0 = 0.f, b1 = 0.f, b2 = 0.f, b3 = 0.f;
#pragma unroll
            for (int c4 = 0; c4 < 16; ++c4) {
                float4 v = cv[c4];            // uniform address -> LDS broadcast
                a0 = fmaf(v.x, x0[c4 * 4 + 0], a0);
                a1 = fmaf(v.y, x0[c4 * 4 + 1], a1);
                a2 = fmaf(v.z, x0[c4 * 4 + 2], a2);
                a3 = fmaf(v.w, x0[c4 * 4 + 3], a3);
                b0 = fmaf(v.x, x1[c4 * 4 + 0], b0);
                b1 = fmaf(v.y, x1[c4 * 4 + 1], b1);
                b2 = fmaf(v.z, x1[c4 * 4 + 2], b2);
                b3 = fmaf(v.w, x1[c4 * 4 + 3], b3);
            }
            const float d0 = bsqs[jj] - 2.f * ((a0 + a1) + (a2 + a3));
            const float d1 = bsqs[jj] - 2.f * ((b0 + b1) + (b2 + b3));
            const int j = ch + jj;
            if (d0 < best0) { best0 = d0; bi0 = j; }
            if (d1 < best1) { best1 = d1; bi1 = j; }
        }
    }

    lidx[tid] = bi0;
    lidx[tid + BLK] = bi1;
    atomicAdd(&hist[bi0], 1u);
    atomicAdd(&hist[bi1], 1u);
    __syncthreads();

    for (int k = tid; k < VOCAB; k += BLK) {
        unsigned h = hist[k];
        if (h) atomicAdd(&counts[k], h);
    }

    // ---- gather quantized, write quantized_st (NCHW), accumulate loss ----
    float lsum = 0.f;
    {
        const int b0 = n0 >> 12, hw0 = n0 & 4095;
        float* q0 = out + OUT_Q_OFF + (size_t)b0 * 262144 + hw0;
        const float* c0 = cb + (size_t)bi0 * HIDDEN;
#pragma unroll
        for (int c = 0; c < HIDDEN; ++c) {
            float q = c0[c];
            float d = q - x0[c];
            lsum = fmaf(d, d, lsum);
            q0[(size_t)c * 4096] = x0[c] + (q - x0[c]);   // straight-through value
        }
        const int b1 = n1 >> 12, hw1 = n1 & 4095;
        float* q1 = out + OUT_Q_OFF + (size_t)b1 * 262144 + hw1;
        const float* c1 = cb + (size_t)bi1 * HIDDEN;
#pragma unroll
        for (int c = 0; c < HIDDEN; ++c) {
            float q = c1[c];
            float d = q - x1[c];
            lsum = fmaf(d, d, lsum);
            q1[(size_t)c * 4096] = x1[c] + (q - x1[c]);
        }
    }
    // wave + block reduce loss
#pragma unroll
    for (int off = 32; off; off >>= 1) lsum += __shfl_down(lsum, off);
    if ((tid & 63) == 0) lred[tid >> 6] = lsum;
    __syncthreads();
    if (tid == 0) atomicAdd(ws_loss, lred[0] + lred[1] + lred[2] + lred[3]);

    // ---- cooperative one_hot row writes (8B-aligned region -> float2) ----
    const size_t oh_base = OUT_OH_OFF + (size_t)blockIdx.x * POS_PER_BLOCK * VOCAB;
    for (int r = 0; r < POS_PER_BLOCK; ++r) {
        const int j = lidx[r];
        float2 z0 = make_float2(0.f, 0.f), z1 = make_float2(0.f, 0.f);
        if ((j >> 2) == tid) {
            if (j & 2) { if (j & 1) z1.y = 1.f; else z1.x = 1.f; }
            else       { if (j & 1) z0.y = 1.f; else z0.x = 1.f; }
        }
        float* p = out + oh_base + (size_t)r * VOCAB + tid * 4;
        *(float2*)(p)     = z0;
        *(float2*)(p + 2) = z1;
    }
}

__global__ void vq_finalize(const unsigned* __restrict__ counts,
                            const float* __restrict__ ws_loss,
                            float* __restrict__ out)
{
    __shared__ double red[4];
    const int tid = threadIdx.x;
    double s = 0.0;
    for (int k = tid; k < VOCAB; k += 256) {
        double p = (double)counts[k] / (double)N_POS;
        s += -p * log(p + 1e-10);
    }
#pragma unroll
    for (int off = 32; off; off >>= 1) s += __shfl_down(s, off);
    if ((tid & 63) == 0) red[tid >> 6] = s;
    __syncthreads();
    if (tid == 0) {
        double e = red[0] + red[1] + red[2] + red[3];
        out[OUT_PPL_OFF] = (float)exp(e);
        out[0] = ws_loss[0] * 1.25f / (float)Q_ELEMS;
    }
}

extern "C" void kernel_launch(void* const* d_in, const int* in_sizes, int n_in,
                              void* d_out, int out_size, void* d_ws, size_t ws_size,
                              hipStream_t stream) {
    const float* in = (const float*)d_in[0];
    const float* cb = (const float*)d_in[1];
    float* out = (float*)d_out;

    float*    ws_loss = (float*)d_ws;                 // 4 B
    unsigned* counts  = (unsigned*)d_ws + 64;         // bytes 256..4352
    float*    bsq     = (float*)d_ws + 2048;          // bytes 8192..12288

    hipMemsetAsync(d_ws, 0, 4352, stream);            // zero loss accum + counts
    vq_bsq<<<4, 256, 0, stream>>>(cb, bsq);
    vq_main<<<256, BLK, 0, stream>>>(in, cb, bsq, out, ws_loss, counts);
    vq_finalize<<<1, 256, 0, stream>>>(counts, ws_loss, out);
}

// Round 2
// 372.289 us; speedup vs baseline: 1.2674x; 1.2674x over previous
//
#include <hip/hip_runtime.h>

#define VOCAB 1024
#define HIDDEN 64
#define N_POS 131072            // 32*64*64 positions
#define Q_ELEMS 8388608         // 32*64*64*64
#define BLK 512
#define BPOS 512                // positions per block
#define CHUNKH 128              // codebook rows per half per LDS chunk
#define NITER 4                 // 512 codes per half / CHUNKH

// d_out layout (floats): [0]=loss, [1..8388608]=quantized_st (NCHW),
// [8388609]=perplexity, [8388610..]=one_hot [131072,1024]
#define OUT_Q_OFF 1
#define OUT_PPL_OFF 8388609
#define OUT_OH_OFF 8388610ULL

__global__ void vq_bsq(const float* __restrict__ cb, float* __restrict__ bsq) {
    int j = blockIdx.x * blockDim.x + threadIdx.x;
    if (j < VOCAB) {
        const float4* r = (const float4*)(cb + (size_t)j * HIDDEN);
        float s = 0.f;
#pragma unroll
        for (int c = 0; c < 16; ++c) {
            float4 v = r[c];
            s += v.x * v.x + v.y * v.y + v.z * v.z + v.w * v.w;
        }
        bsq[j] = s;
    }
}

// 512 threads: half h = tid>>8 scans codebook rows [512h, 512h+512) for the
// block's 512 positions; thread t handles position pair (base+pp, base+pp+256),
// pp = tid&255. Results merged via LDS; thread t then OWNS position base+tid.
__global__ __launch_bounds__(BLK, 2) void vq_main(
    const float* __restrict__ in, const float* __restrict__ cb,
    const float* __restrict__ bsq, float* __restrict__ out,
    float* __restrict__ ws_loss, unsigned* __restrict__ counts)
{
    __shared__ float cbs[2][CHUNKH * HIDDEN];   // 64 KB
    __shared__ float bsqs[2][CHUNKH];
    __shared__ float md[2][2][256];             // [half][posslot][pp]
    __shared__ int   mi[2][2][256];
    __shared__ unsigned hist[VOCAB];
    __shared__ float lred[8];

    const int tid = threadIdx.x;
    const int h   = tid >> 8;          // wave-uniform (waves 0-3 h=0, 4-7 h=1)
    const int pp  = tid & 255;
    const int base = blockIdx.x * BPOS;
    const int b    = base >> 12;       // NCHW batch index; uniform per block
    const int n0 = base + pp;
    const int n1 = n0 + 256;
    const int hw0 = n0 & 4095, hw1 = n1 & 4095;

    // ---- load the two positions' 64-dim vectors into registers ----
    float x0[HIDDEN], x1[HIDDEN];
    {
        const float* p0 = in + (size_t)b * 262144 + hw0;
        const float* p1 = in + (size_t)b * 262144 + hw1;
#pragma unroll
        for (int c = 0; c < HIDDEN; ++c) {
            x0[c] = p0[(size_t)c * 4096];   // coalesced across lanes
            x1[c] = p1[(size_t)c * 4096];
        }
    }

    for (int k = tid; k < VOCAB; k += BLK) hist[k] = 0u;

    float best0 = 3.4e38f, best1 = 3.4e38f;
    int bi0 = 0, bi1 = 0;
    const float* ch_cbs = cbs[h];
    const float* ch_bsq = bsqs[h];
    const int jbase = h * 512;

    for (int it = 0; it < NITER; ++it) {
        __syncthreads();
        {   // stage this half's 128 rows (32 KB) into its LDS buffer
            const float4* src = (const float4*)(cb + (size_t)(jbase + it * CHUNKH) * HIDDEN);
            float4* dst = (float4*)cbs[h];
#pragma unroll
            for (int k = 0; k < 8; ++k) dst[pp + k * 256] = src[pp + k * 256];
            if (pp < CHUNKH) bsqs[h][pp] = bsq[jbase + it * CHUNKH + pp];
        }
        __syncthreads();

#pragma unroll 2
        for (int jj = 0; jj < CHUNKH; ++jj) {
            const float4* cv = (const float4*)(ch_cbs + jj * HIDDEN);
            float a0 = 0.f, a1 = 0.f, a2 = 0.f, a3 = 0.f;
            float c0 = 0.f, c1 = 0.f, c2 = 0.f, c3 = 0.f;
#pragma unroll
            for (int c4 = 0; c4 < 16; ++c4) {
                float4 v = cv[c4];            // uniform address -> LDS broadcast
                a0 = fmaf(v.x, x0[c4 * 4 + 0], a0);
                a1 = fmaf(v.y, x0[c4 * 4 + 1], a1);
                a2 = fmaf(v.z, x0[c4 * 4 + 2], a2);
                a3 = fmaf(v.w, x0[c4 * 4 + 3], a3);
                c0 = fmaf(v.x, x1[c4 * 4 + 0], c0);
                c1 = fmaf(v.y, x1[c4 * 4 + 1], c1);
                c2 = fmaf(v.z, x1[c4 * 4 + 2], c2);
                c3 = fmaf(v.w, x1[c4 * 4 + 3], c3);
            }
            const float d0 = ch_bsq[jj] - 2.f * ((a0 + a1) + (a2 + a3));
            const float d1 = ch_bsq[jj] - 2.f * ((c0 + c1) + (c2 + c3));
            const int j = jbase + it * CHUNKH + jj;
            if (d0 < best0) { best0 = d0; bi0 = j; }
            if (d1 < best1) { best1 = d1; bi1 = j; }
        }
    }

    // ---- merge halves; thread t then owns position n = base + tid ----
    md[h][0][pp] = best0; mi[h][0][pp] = bi0;
    md[h][1][pp] = best1; mi[h][1][pp] = bi1;
    __syncthreads();

    const int slot = h;   // t<256 owns posslot 0 (n0), t>=256 owns posslot 1 (n1)
    const float dh0 = md[0][slot][pp];
    const float dh1 = md[1][slot][pp];
    const int   ih0 = mi[0][slot][pp];
    const int   ih1 = mi[1][slot][pp];
    const int jf = (dh1 < dh0) ? ih1 : ih0;   // tie -> lower index (half 0)

    atomicAdd(&hist[jf], 1u);

    // ---- quantized_st (NCHW) + loss for owned position ----
    const int n = base + tid;
    const int hwn = n & 4095;
    float* q = out + OUT_Q_OFF + (size_t)b * 262144 + hwn;
    const float* cbr = cb + (size_t)jf * HIDDEN;
    float lsum = 0.f;
    if (h == 0) {
#pragma unroll
        for (int c = 0; c < HIDDEN; ++c) {
            float qv = cbr[c];
            float d = qv - x0[c];
            lsum = fmaf(d, d, lsum);
            q[(size_t)c * 4096] = x0[c] + (qv - x0[c]);   // straight-through value
        }
    } else {
#pragma unroll
        for (int c = 0; c < HIDDEN; ++c) {
            float qv = cbr[c];
            float d = qv - x1[c];
            lsum = fmaf(d, d, lsum);
            q[(size_t)c * 4096] = x1[c] + (qv - x1[c]);
        }
    }

    // ---- scatter the single 1.0 (zeros laid down by hipMemsetAsync) ----
    out[OUT_OH_OFF + (size_t)n * VOCAB + jf] = 1.0f;

    // ---- block-reduce loss, flush histogram ----
#pragma unroll
    for (int off = 32; off; off >>= 1) lsum += __shfl_down(lsum, off);
    if ((tid & 63) == 0) lred[tid >> 6] = lsum;
    __syncthreads();
    if (tid == 0) {
        float s = 0.f;
#pragma unroll
        for (int w = 0; w < 8; ++w) s += lred[w];
        atomicAdd(ws_loss, s);
    }
    for (int k = tid; k < VOCAB; k += BLK) {
        unsigned hcnt = hist[k];
        if (hcnt) atomicAdd(&counts[k], hcnt);
    }
}

__global__ void vq_finalize(const unsigned* __restrict__ counts,
                            const float* __restrict__ ws_loss,
                            float* __restrict__ out)
{
    __shared__ double red[4];
    const int tid = threadIdx.x;
    double s = 0.0;
    for (int k = tid; k < VOCAB; k += 256) {
        double p = (double)counts[k] / (double)N_POS;
        s += -p * log(p + 1e-10);
    }
#pragma unroll
    for (int off = 32; off; off >>= 1) s += __shfl_down(s, off);
    if ((tid & 63) == 0) red[tid >> 6] = s;
    __syncthreads();
    if (tid == 0) {
        double e = red[0] + red[1] + red[2] + red[3];
        out[OUT_PPL_OFF] = (float)exp(e);
        out[0] = ws_loss[0] * 1.25f / (float)Q_ELEMS;
    }
}

extern "C" void kernel_launch(void* const* d_in, const int* in_sizes, int n_in,
                              void* d_out, int out_size, void* d_ws, size_t ws_size,
                              hipStream_t stream) {
    const float* in = (const float*)d_in[0];
    const float* cb = (const float*)d_in[1];
    float* out = (float*)d_out;

    float*    ws_loss = (float*)d_ws;                 // 4 B
    unsigned* counts  = (unsigned*)d_ws + 64;         // bytes 256..4352
    float*    bsq     = (float*)d_ws + 2048;          // bytes 8192..12288

    // bulk-zero the one_hot region (536 MB) with the runtime's tuned memset
    hipMemsetAsync(out + OUT_OH_OFF, 0, (size_t)N_POS * VOCAB * sizeof(float), stream);
    hipMemsetAsync(d_ws, 0, 4352, stream);            // zero loss accum + counts
    vq_bsq<<<4, 256, 0, stream>>>(cb, bsq);
    vq_main<<<256, BLK, 0, stream>>>(in, cb, bsq, out, ws_loss, counts);
    vq_finalize<<<1, 256, 0, stream>>>(counts, ws_loss, out);
}

// Round 3
// 170.526 us; speedup vs baseline: 2.7669x; 2.1832x over previous
//
#include <hip/hip_runtime.h>

#define VOCAB 1024
#define HIDDEN 64
#define N_POS 131072            // 32*64*64 positions
#define Q_ELEMS 8388608
#define BPOS 256                // positions per block
#define NBLK 512                // N_POS / BPOS

// d_out layout (floats): [0]=loss, [1..8388608]=quantized_st (NCHW),
// [8388609]=perplexity, [8388610..]=one_hot [131072,1024]
#define OUT_Q_OFF 1
#define OUT_PPL_OFF 8388609
#define OUT_OH_OFF 8388610ULL

typedef __attribute__((ext_vector_type(8))) short short8v;  // bf16x8 MFMA frag
typedef __attribute__((ext_vector_type(4))) float f32x4;

__device__ __forceinline__ short bf16r(float f) {
    union { float f; unsigned u; } v; v.f = f;
    unsigned r = v.u + 0x7FFFu + ((v.u >> 16) & 1u);   // RNE
    return (short)(r >> 16);
}

__global__ void vq_bsq(const float* __restrict__ cb, float* __restrict__ bsq) {
    int j = blockIdx.x * blockDim.x + threadIdx.x;
    if (j < VOCAB) {
        const float4* r = (const float4*)(cb + (size_t)j * HIDDEN);
        float s = 0.f;
#pragma unroll
        for (int c = 0; c < 16; ++c) {
            float4 v = r[c];
            s += v.x * v.x + v.y * v.y + v.z * v.z + v.w * v.w;
        }
        bsq[j] = -0.5f * s;        // pre-scaled: argmin d <=> argmax(dot - 0.5*bsq)
    }
}

// Block: 256 threads (4 waves), 256 positions. MFMA D[code][pos] tiles:
// A = codebook (rows=codes, from swizzled LDS bf16), B = x (cols=positions,
// bf16 frags in registers), C init = -0.5*|c|^2 per code-row.
// Running argmax per position via index-packed-in-mantissa + v_max_f32.
__global__ __launch_bounds__(256, 2) void vq_main(
    const float* __restrict__ in, const float* __restrict__ cb,
    const float* __restrict__ bsq, float* __restrict__ out,
    float* __restrict__ ws_loss, unsigned* __restrict__ counts)
{
    __shared__ short cbs[256 * HIDDEN];     // 32 KB, one 256-code chunk, swizzled
    __shared__ float bsqs[256];             // -0.5*|c|^2 for the chunk
    __shared__ int   idx_lds[BPOS];
    __shared__ unsigned hist[VOCAB];
    __shared__ float lred[4];

    const int tid  = threadIdx.x;
    const int wid  = tid >> 6;
    const int lane = tid & 63;
    const int l15  = lane & 15;
    const int kg   = lane >> 4;        // k-group 0..3
    const int kg4  = kg << 2;
    const int kgb  = kg << 4;          // byte offset of this k-group's 8 bf16

    const int base = blockIdx.x * BPOS;
    const int b    = base >> 12;       // uniform per block
    const int hw0  = base & 4095;

    for (int k = tid; k < VOCAB; k += 256) hist[k] = 0u;

    // ---- load x fragments: wave covers positions [wid*64, wid*64+64) ----
    // B-frag lane mapping: col = lane&15 (position), k = kg*8+e (+32 for kh=1)
    short8v xf[4][2];
#pragma unroll
    for (int bt = 0; bt < 4; ++bt) {
#pragma unroll
        for (int kh = 0; kh < 2; ++kh) {
            const float* xp = in + (size_t)b * 262144
                            + (size_t)(kh * 32 + kg * 8) * 4096
                            + hw0 + wid * 64 + bt * 16 + l15;
            short8v v;
#pragma unroll
            for (int e = 0; e < 8; ++e) v[e] = bf16r(xp[(size_t)e * 4096]);
            xf[bt][kh] = v;
        }
    }

    float rm[4];
#pragma unroll
    for (int bt = 0; bt < 4; ++bt) rm[bt] = -3.4e38f;

    for (int ch = 0; ch < 4; ++ch) {
        __syncthreads();
        {   // stage 256 codes as bf16, XOR-swizzled (T2): byte ^= (row&7)<<4
            const float4* src = (const float4*)(cb + (size_t)ch * 256 * HIDDEN);
#pragma unroll
            for (int it = 0; it < 16; ++it) {
                int i = tid + it * 256;
                int row = i >> 4, c4 = i & 15;
                float4 v = src[i];
                unsigned lo = ((unsigned)(unsigned short)bf16r(v.x))
                            | ((unsigned)(unsigned short)bf16r(v.y) << 16);
                unsigned hi = ((unsigned)(unsigned short)bf16r(v.z))
                            | ((unsigned)(unsigned short)bf16r(v.w) << 16);
                int boff = row * 128 + ((c4 * 8) ^ ((row & 7) << 4));
                *(uint2*)((char*)cbs + boff) = make_uint2(lo, hi);
            }
            bsqs[tid] = bsq[ch * 256 + tid];
        }
        __syncthreads();

        for (int ct = 0; ct < 16; ++ct) {
            const int rbase = ct * 16 + l15;          // A-frag row = code
            const char* arow = (const char*)cbs + rbase * 128;
            const int sw = (rbase & 7) << 4;
            short8v a0 = *(const short8v*)(arow + (kgb ^ sw));          // k 0..31
            short8v a1 = *(const short8v*)(arow + ((64 + kgb) ^ sw));   // k 32..63
            f32x4 bsq4 = *(const f32x4*)&bsqs[ct * 16 + kg4];
            const unsigned jb = (unsigned)(ch * 256 + ct * 16 + kg4);
#pragma unroll
            for (int bt = 0; bt < 4; ++bt) {
                f32x4 acc = bsq4;
                acc = __builtin_amdgcn_mfma_f32_16x16x32_bf16(a0, xf[bt][0], acc, 0, 0, 0);
                acc = __builtin_amdgcn_mfma_f32_16x16x32_bf16(a1, xf[bt][1], acc, 0, 0, 0);
#pragma unroll
                for (int r = 0; r < 4; ++r) {
                    unsigned pj = (__float_as_uint(acc[r]) & 0xFFFFFC00u) | (jb + r);
                    rm[bt] = fmaxf(rm[bt], __uint_as_float(pj));
                }
            }
        }
    }

    // ---- cross-lane reduce (k-groups hold disjoint code-rows, same col) ----
#pragma unroll
    for (int bt = 0; bt < 4; ++bt) {
        float m = rm[bt];
        m = fmaxf(m, __shfl_xor(m, 16));
        m = fmaxf(m, __shfl_xor(m, 32));
        if (kg == 0) {
            int j = (int)(__float_as_uint(m) & 1023u);
            idx_lds[wid * 64 + bt * 16 + l15] = j;
            atomicAdd(&hist[j], 1u);
        }
    }
    __syncthreads();

    // ---- gather fp32 code row, write quantized_st (== q), loss ----
    const int jf = idx_lds[tid];
    const float* cr = cb + (size_t)jf * HIDDEN;
    const float* xp = in  + (size_t)b * 262144 + hw0 + tid;
    float*       qp = out + OUT_Q_OFF + (size_t)b * 262144 + hw0 + tid;
    float lsum = 0.f;
#pragma unroll
    for (int c = 0; c < HIDDEN; ++c) {
        float q = cr[c];
        float x = xp[(size_t)c * 4096];
        float d = q - x;
        lsum = fmaf(d, d, lsum);
        qp[(size_t)c * 4096] = q;     // x + (q - x) == q
    }

    // ---- flush histogram, reduce loss ----
    for (int k = tid; k < VOCAB; k += 256) {
        unsigned h = hist[k];
        if (h) atomicAdd(&counts[k], h);
    }
#pragma unroll
    for (int off = 32; off; off >>= 1) lsum += __shfl_down(lsum, off);
    if (lane == 0) lred[wid] = lsum;
    __syncthreads();
    if (tid == 0) atomicAdd(ws_loss, lred[0] + lred[1] + lred[2] + lred[3]);

    // ---- one_hot rows for this block's 256 positions (zeros + the 1.0) ----
    // region is only 8B-aligned -> float2 stores
    float* ohb = out + OUT_OH_OFF + (size_t)base * VOCAB;
    for (int r = 0; r < BPOS; ++r) {
        const int jr = idx_lds[r];
        const int s0 = jr >> 1, e0 = jr & 1;
        float2 v0 = make_float2(0.f, 0.f), v1 = v0;
        if (s0 == tid)       { if (e0) v0.y = 1.f; else v0.x = 1.f; }
        if (s0 == tid + 256) { if (e0) v1.y = 1.f; else v1.x = 1.f; }
        float2* p = (float2*)(ohb + (size_t)r * VOCAB);
        p[tid]       = v0;
        p[tid + 256] = v1;
    }
}

__global__ void vq_finalize(const unsigned* __restrict__ counts,
                            const float* __restrict__ ws_loss,
                            float* __restrict__ out)
{
    __shared__ double red[4];
    const int tid = threadIdx.x;
    double s = 0.0;
    for (int k = tid; k < VOCAB; k += 256) {
        double p = (double)counts[k] / (double)N_POS;
        s += -p * log(p + 1e-10);
    }
#pragma unroll
    for (int off = 32; off; off >>= 1) s += __shfl_down(s, off);
    if ((tid & 63) == 0) red[tid >> 6] = s;
    __syncthreads();
    if (tid == 0) {
        double e = red[0] + red[1] + red[2] + red[3];
        out[OUT_PPL_OFF] = (float)exp(e);
        out[0] = ws_loss[0] * 1.25f / (float)Q_ELEMS;
    }
}

extern "C" void kernel_launch(void* const* d_in, const int* in_sizes, int n_in,
                              void* d_out, int out_size, void* d_ws, size_t ws_size,
                              hipStream_t stream) {
    const float* in = (const float*)d_in[0];
    const float* cb = (const float*)d_in[1];
    float* out = (float*)d_out;

    float*    ws_loss = (float*)d_ws;                 // 4 B
    unsigned* counts  = (unsigned*)d_ws + 64;         // bytes 256..4352
    float*    bsq     = (float*)d_ws + 2048;          // bytes 8192..12288

    hipMemsetAsync(d_ws, 0, 4352, stream);            // zero loss accum + counts
    vq_bsq<<<4, 256, 0, stream>>>(cb, bsq);
    vq_main<<<NBLK, 256, 0, stream>>>(in, cb, bsq, out, ws_loss, counts);
    vq_finalize<<<1, 256, 0, stream>>>(counts, ws_loss, out);
}

// Round 4
// 163.330 us; speedup vs baseline: 2.8888x; 1.0441x over previous
//
#include <hip/hip_runtime.h>

#define VOCAB 1024
#define HIDDEN 64
#define N_POS 131072            // 32*64*64 positions
#define Q_ELEMS 8388608
#define BPOS 256                // positions per block
#define NBLK 512                // N_POS / BPOS

// d_out layout (floats): [0]=loss, [1..8388608]=quantized_st (NCHW),
// [8388609]=perplexity, [8388610..]=one_hot [131072,1024]
#define OUT_Q_OFF 1
#define OUT_PPL_OFF 8388609
#define OUT_OH_OFF 8388610ULL

typedef __attribute__((ext_vector_type(8))) short short8v;  // bf16x8 MFMA frag
typedef __attribute__((ext_vector_type(4))) float f32x4;

__device__ __forceinline__ short bf16r(float f) {
    union { float f; unsigned u; } v; v.f = f;
    unsigned r = v.u + 0x7FFFu + ((v.u >> 16) & 1u);   // RNE
    return (short)(r >> 16);
}

__global__ void vq_bsq(const float* __restrict__ cb, float* __restrict__ bsq) {
    int j = blockIdx.x * blockDim.x + threadIdx.x;
    if (j < VOCAB) {
        const float4* r = (const float4*)(cb + (size_t)j * HIDDEN);
        float s = 0.f;
#pragma unroll
        for (int c = 0; c < 16; ++c) {
            float4 v = r[c];
            s += v.x * v.x + v.y * v.y + v.z * v.z + v.w * v.w;
        }
        bsq[j] = -0.5f * s;        // argmin d <=> argmax(dot - 0.5*|c|^2)
    }
}

// Block: 256 threads (4 waves), 256 positions. MFMA D[code][pos];
// A = codebook (swizzled LDS bf16), B = x frags in registers,
// C init = -0.5*|c|^2. one_hot ZERO-stores are interleaved into the chunk
// loop (only the 1.0 per row is data-dependent; zeros overlap with MFMA).
__global__ __launch_bounds__(256, 2) void vq_main(
    const float* __restrict__ in, const float* __restrict__ cb,
    const float* __restrict__ bsq, float* __restrict__ out,
    float* __restrict__ ws_loss, unsigned* __restrict__ counts)
{
    __shared__ short cbs[256 * HIDDEN];     // 32 KB, one 256-code chunk, swizzled
    __shared__ float bsqs[256];
    __shared__ int   idx_lds[BPOS];
    __shared__ unsigned hist[VOCAB];
    __shared__ float lred[4];

    const int tid  = threadIdx.x;
    const int wid  = tid >> 6;
    const int lane = tid & 63;
    const int l15  = lane & 15;
    const int kg   = lane >> 4;        // k-group 0..3
    const int kg4  = kg << 2;
    const int kgb  = kg << 4;

    const int base = blockIdx.x * BPOS;
    const int b    = base >> 12;       // uniform per block
    const int hw0  = base & 4095;

    for (int k = tid; k < VOCAB; k += 256) hist[k] = 0u;

    // ---- one_hot zero layout: flat 1 MB slice, starts at byte%16 == 8 ----
    float* ohflat = out + OUT_OH_OFF + (size_t)base * VOCAB;   // 262144 floats
    float4* oh4 = (float4*)(ohflat + 2);                       // 16B aligned
    const float4 z4 = make_float4(0.f, 0.f, 0.f, 0.f);
    if (tid == 0)   *(float2*)ohflat = make_float2(0.f, 0.f);              // head
    if (tid == 255) *(float2*)(ohflat + 262142) = make_float2(0.f, 0.f);   // tail

    // ---- load x fragments: wave covers positions [wid*64, wid*64+64) ----
    short8v xf[4][2];
#pragma unroll
    for (int bt = 0; bt < 4; ++bt) {
#pragma unroll
        for (int kh = 0; kh < 2; ++kh) {
            const float* xp = in + (size_t)b * 262144
                            + (size_t)(kh * 32 + kg * 8) * 4096
                            + hw0 + wid * 64 + bt * 16 + l15;
            short8v v;
#pragma unroll
            for (int e = 0; e < 8; ++e) v[e] = bf16r(xp[(size_t)e * 4096]);
            xf[bt][kh] = v;
        }
    }

    float rm[4];
#pragma unroll
    for (int bt = 0; bt < 4; ++bt) rm[bt] = -3.4e38f;

    for (int ch = 0; ch < 4; ++ch) {
        __syncthreads();
        {   // stage 256 codes as bf16, XOR-swizzled: byte ^= (row&7)<<4
            const float4* src = (const float4*)(cb + (size_t)ch * 256 * HIDDEN);
#pragma unroll
            for (int it = 0; it < 16; ++it) {
                int i = tid + it * 256;
                int row = i >> 4, c4 = i & 15;
                float4 v = src[i];
                unsigned lo = ((unsigned)(unsigned short)bf16r(v.x))
                            | ((unsigned)(unsigned short)bf16r(v.y) << 16);
                unsigned hi = ((unsigned)(unsigned short)bf16r(v.z))
                            | ((unsigned)(unsigned short)bf16r(v.w) << 16);
                int boff = row * 128 + ((c4 * 8) ^ ((row & 7) << 4));
                *(uint2*)((char*)cbs + boff) = make_uint2(lo, hi);
            }
            bsqs[tid] = bsq[ch * 256 + tid];
        }
        __syncthreads();

        // issue this chunk's share of one_hot zeros (fire-and-forget; they
        // drain to HBM underneath the MFMA phase, paced by the end barrier)
#pragma unroll 8
        for (int it = ch * 64; it < ch * 64 + 64; ++it) {
            int idx = it * 256 + tid;
            if (idx < 65535) oh4[idx] = z4;
        }

        for (int ct = 0; ct < 16; ++ct) {
            const int rbase = ct * 16 + l15;          // A-frag row = code
            const char* arow = (const char*)cbs + rbase * 128;
            const int sw = (rbase & 7) << 4;
            short8v a0 = *(const short8v*)(arow + (kgb ^ sw));          // k 0..31
            short8v a1 = *(const short8v*)(arow + ((64 + kgb) ^ sw));   // k 32..63
            f32x4 bsq4 = *(const f32x4*)&bsqs[ct * 16 + kg4];
            const unsigned jb = (unsigned)(ch * 256 + ct * 16 + kg4);
#pragma unroll
            for (int bt = 0; bt < 4; ++bt) {
                f32x4 acc = bsq4;
                acc = __builtin_amdgcn_mfma_f32_16x16x32_bf16(a0, xf[bt][0], acc, 0, 0, 0);
                acc = __builtin_amdgcn_mfma_f32_16x16x32_bf16(a1, xf[bt][1], acc, 0, 0, 0);
#pragma unroll
                for (int r = 0; r < 4; ++r) {
                    unsigned pj = (__float_as_uint(acc[r]) & 0xFFFFFC00u) | (jb + r);
                    rm[bt] = fmaxf(rm[bt], __uint_as_float(pj));
                }
            }
        }
    }

    // ---- cross-lane reduce (k-groups hold disjoint code-rows, same col) ----
#pragma unroll
    for (int bt = 0; bt < 4; ++bt) {
        float m = rm[bt];
        m = fmaxf(m, __shfl_xor(m, 16));
        m = fmaxf(m, __shfl_xor(m, 32));
        if (kg == 0) {
            int j = (int)(__float_as_uint(m) & 1023u);
            idx_lds[wid * 64 + bt * 16 + l15] = j;
            atomicAdd(&hist[j], 1u);
        }
    }
    __syncthreads();   // also drains vmcnt(0): all zero-stores committed to L2

    // ---- gather fp32 code row, write quantized_st (== q), loss ----
    const int jf = idx_lds[tid];
    const float* cr = cb + (size_t)jf * HIDDEN;
    const float* xp = in  + (size_t)b * 262144 + hw0 + tid;
    float*       qp = out + OUT_Q_OFF + (size_t)b * 262144 + hw0 + tid;
    float lsum = 0.f;
#pragma unroll
    for (int c = 0; c < HIDDEN; ++c) {
        float q = cr[c];
        float x = xp[(size_t)c * 4096];
        float d = q - x;
        lsum = fmaf(d, d, lsum);
        qp[(size_t)c * 4096] = q;     // x + (q - x) == q
    }

    // ---- the data-dependent 1.0 per row (zeros already committed) ----
    ohflat[(size_t)tid * VOCAB + jf] = 1.0f;

    // ---- flush histogram, reduce loss ----
    for (int k = tid; k < VOCAB; k += 256) {
        unsigned h = hist[k];
        if (h) atomicAdd(&counts[k], h);
    }
#pragma unroll
    for (int off = 32; off; off >>= 1) lsum += __shfl_down(lsum, off);
    if (lane == 0) lred[wid] = lsum;
    __syncthreads();
    if (tid == 0) atomicAdd(ws_loss, lred[0] + lred[1] + lred[2] + lred[3]);
}

__global__ void vq_finalize(const unsigned* __restrict__ counts,
                            const float* __restrict__ ws_loss,
                            float* __restrict__ out)
{
    __shared__ double red[4];
    const int tid = threadIdx.x;
    double s = 0.0;
    for (int k = tid; k < VOCAB; k += 256) {
        double p = (double)counts[k] / (double)N_POS;
        s += -p * log(p + 1e-10);
    }
#pragma unroll
    for (int off = 32; off; off >>= 1) s += __shfl_down(s, off);
    if ((tid & 63) == 0) red[tid >> 6] = s;
    __syncthreads();
    if (tid == 0) {
        double e = red[0] + red[1] + red[2] + red[3];
        out[OUT_PPL_OFF] = (float)exp(e);
        out[0] = ws_loss[0] * 1.25f / (float)Q_ELEMS;
    }
}

extern "C" void kernel_launch(void* const* d_in, const int* in_sizes, int n_in,
                              void* d_out, int out_size, void* d_ws, size_t ws_size,
                              hipStream_t stream) {
    const float* in = (const float*)d_in[0];
    const float* cb = (const float*)d_in[1];
    float* out = (float*)d_out;

    float*    ws_loss = (float*)d_ws;                 // 4 B
    unsigned* counts  = (unsigned*)d_ws + 64;         // bytes 256..4352
    float*    bsq     = (float*)d_ws + 2048;          // bytes 8192..12288

    hipMemsetAsync(d_ws, 0, 4352, stream);            // zero loss accum + counts
    vq_bsq<<<4, 256, 0, stream>>>(cb, bsq);
    vq_main<<<NBLK, 256, 0, stream>>>(in, cb, bsq, out, ws_loss, counts);
    vq_finalize<<<1, 256, 0, stream>>>(counts, ws_loss, out);
}